// Round 8
// baseline (216.976 us; speedup 1.0000x reference)
//
#include <hip/hip_runtime.h>
#include <stdint.h>

#define GAMMA 0.002f
#define MDIM 4096
#define NDIM 8192
#define KDIM 512

typedef short v8s __attribute__((ext_vector_type(8)));
typedef float v4f __attribute__((ext_vector_type(4)));

__device__ __forceinline__ unsigned short f32_to_bf16_rne(float f) {
    union { float f; uint32_t u; } v; v.f = f;
    uint32_t u = v.u;
    return (unsigned short)((u + 0x7fffu + ((u >> 16) & 1u)) >> 16);
}

__device__ __forceinline__ void gl_lds16(const void* g, void* l) {
    __builtin_amdgcn_global_load_lds(
        (const __attribute__((address_space(1))) uint32_t*)g,
        (__attribute__((address_space(3))) uint32_t*)l, 16, 0, 0);
}

// One block per row: convert 512 fp32 -> bf16 (RNE) and emit -gamma*sum(x^2).
__global__ __launch_bounds__(256) void convert_rows(
    const float* __restrict__ in, unsigned short* __restrict__ outb,
    float* __restrict__ neg_g_sq) {
    int row = blockIdx.x;
    const float* src = in + (size_t)row * KDIM;
    unsigned short* dst = outb + (size_t)row * KDIM;
    int t = threadIdx.x;
    float2 f = ((const float2*)src)[t];
    ushort2 b;
    b.x = f32_to_bf16_rne(f.x);
    b.y = f32_to_bf16_rne(f.y);
    ((ushort2*)dst)[t] = b;
    float s = f.x * f.x + f.y * f.y;
    #pragma unroll
    for (int off = 32; off > 0; off >>= 1) s += __shfl_down(s, off, 64);
    __shared__ float red[4];
    if ((t & 63) == 0) red[t >> 6] = s;
    __syncthreads();
    if (t == 0) neg_g_sq[row] = -GAMMA * (red[0] + red[1] + red[2] + red[3]);
}

// v6: same schedule as v4/v5 (BK=32, triple buffer, vmcnt(4), L2 partition,
// setprio). Two LDS-pipe changes:
//  (1) K-major LDS layout [chunk q][row r] (granule addr = q*2048 + r*16):
//      lanes 0-15 read 16 CONSECUTIVE granules -> 2-way bank access (free),
//      replacing the 4-way-conflicted 64-B-row XOR layout.
//  (2) epilogue LDS transpose removed -> direct v4f stores (r1 vs r3: equal
//      wall time, and it burned ~9 us of LDS-pipe occupancy per CU).
// C[m,n] = exp(arow[m] + ccol[n] + 2*gamma*dot(x[m], sv[n]))
__global__ __launch_bounds__(256, 3) void rbf_gemm(
    const unsigned short* __restrict__ A,   // [4096,512] bf16
    const unsigned short* __restrict__ B,   // [8192,512] bf16
    const float* __restrict__ arow,         // [4096]  = -g*||x||^2
    const float* __restrict__ ccol,         // [8192]  = -g*||sv||^2
    float* __restrict__ out) {

    // LDS: 3 buffers x (A 8 KiB + B 8 KiB) = 48 KiB at 0..49151
    //      sb_r (128 f32) at 49152, sb_c (128 f32) at 49664.  total 50176 B.
    __shared__ __align__(16) char smem[50176];

    const int tid  = threadIdx.x;
    const int lane = tid & 63;
    const int wave = tid >> 6;          // 0..3
    const int wm   = wave >> 1;         // 0..1 : 64-row slice
    const int wn   = wave & 1;          // 0..1 : 64-col slice

    // L2-aware partition: xcd = bid&7 (round-robin dispatch), region 16m x 16n.
    const int bid = blockIdx.x;
    const int xcd = bid & 7;
    const int idx = bid >> 3;                       // 0..255 within region
    const int mt  = ((xcd & 1) << 4) | (idx & 15);  // 0..31
    const int nt  = ((xcd >> 1) << 4) | (idx >> 4); // 0..63
    const int row0 = mt << 7;
    const int col0 = nt << 7;

    // ---- staging, K-major granules: granule g = c*128 + r  (c=chunk 0..3,
    // r=row 0..127). Thread tid writes granules {tid, tid+256} at linear LDS
    // offsets {tid*16, tid*16+4096}; global source supplies (r=tid&127,
    // c=tid>>7) and (r, c+2) -> per-row byte offsets c*16 and c*16+32.
    const int rT = tid & 127;                        // row in tile
    const int cT = tid >> 7;                         // 0..1
    const char* aS = (const char*)A + ((size_t)(row0 + rT) << 10) + (cT << 4);
    const char* bS = (const char*)B + ((size_t)(col0 + rT) << 10) + (cT << 4);
    char* dA = smem + tid * 16;
    char* dB = smem + 8192 + tid * 16;

    #define STAGE(t)                                                          \
      do {                                                                    \
        const int _b = ((t) % 3) * 16384;                                     \
        const char* _sa = aS + (t) * 64;                                      \
        const char* _sb = bS + (t) * 64;                                      \
        gl_lds16(_sa,       dA + _b);                                         \
        gl_lds16(_sa + 32,  dA + _b + 4096);                                  \
        gl_lds16(_sb,       dB + _b);                                         \
        gl_lds16(_sb + 32,  dB + _b + 4096);                                  \
      } while (0)

    // ---- fragment addresses (K-major, conflict-free) ----
    const int q   = lane >> 4;          // 0..3 : k-chunk
    const int l15 = lane & 15;
    const int aOff = q * 2048 + wm * 1024 + l15 * 16;          // + i*256
    const int bOff = 8192 + q * 2048 + wn * 1024 + l15 * 16;   // + j*256

    v4f acc[4][4];
    #pragma unroll
    for (int i = 0; i < 4; ++i)
        #pragma unroll
        for (int j = 0; j < 4; ++j) acc[i][j] = (v4f)0.0f;

    // prologue: 2 tiles in flight; bias loads; wait tile0 (vmcnt: 8 out, keep 4)
    STAGE(0); STAGE(1);
    if (tid < 128) ((float*)(smem + 49152))[tid] = arow[row0 + tid];
    else           ((float*)(smem + 49664))[tid - 128] = ccol[col0 + tid - 128];
    asm volatile("s_waitcnt vmcnt(4)" ::: "memory");
    __builtin_amdgcn_s_barrier();

    #pragma unroll
    for (int t = 0; t < 16; ++t) {
        if (t + 2 < 16) STAGE(t + 2);
        const int bo = (t % 3) * 16384;
        v8s af[4], bf[4];
        #pragma unroll
        for (int i = 0; i < 4; ++i) af[i] = *(const v8s*)(smem + bo + aOff + i * 256);
        #pragma unroll
        for (int j = 0; j < 4; ++j) bf[j] = *(const v8s*)(smem + bo + bOff + j * 256);
        __builtin_amdgcn_s_setprio(1);
        #pragma unroll
        for (int i = 0; i < 4; ++i)
            #pragma unroll
            for (int j = 0; j < 4; ++j)
                acc[i][j] = __builtin_amdgcn_mfma_f32_16x16x32_bf16(
                    bf[j], af[i], acc[i][j], 0, 0, 0);
        __builtin_amdgcn_s_setprio(0);
        if (t < 14)      asm volatile("s_waitcnt vmcnt(4)" ::: "memory");
        else if (t == 14) asm volatile("s_waitcnt vmcnt(0)" ::: "memory");
        __builtin_amdgcn_s_barrier();
    }
    #undef STAGE

    // ---- epilogue: bias+exp in-register, DIRECT v4f stores (no LDS pass)
    const float tg = 2.0f * GAMMA;
    const float* sbr = (const float*)(smem + 49152);
    const float* sbc = (const float*)(smem + 49664);
    #pragma unroll
    for (int i = 0; i < 4; ++i) {
        const int r_l = wm * 64 + i * 16 + l15;
        const float ra = sbr[r_l];
        float* gp = out + (size_t)(row0 + r_l) * NDIM + col0 + wn * 64 + (q << 2);
        #pragma unroll
        for (int j = 0; j < 4; ++j) {
            v4f o;
            #pragma unroll
            for (int v = 0; v < 4; ++v) {
                const int c_l = wn * 64 + j * 16 + (q << 2) + v;
                o[v] = __expf(fmaf(tg, acc[i][j][v], ra + sbc[c_l]));
            }
            *(v4f*)(gp + j * 16) = o;
        }
    }
}

extern "C" void kernel_launch(void* const* d_in, const int* in_sizes, int n_in,
                              void* d_out, int out_size, void* d_ws, size_t ws_size,
                              hipStream_t stream) {
    const float* x  = (const float*)d_in[0];   // [4096,512]
    const float* sv = (const float*)d_in[1];   // [8192,512]
    float* out = (float*)d_out;

    // ws layout: xb (4 MiB) | svb (8 MiB) | arow (16 KiB) | ccol (32 KiB)
    unsigned short* xb  = (unsigned short*)d_ws;
    unsigned short* svb = xb + (size_t)MDIM * KDIM;
    float* arow = (float*)(svb + (size_t)NDIM * KDIM);
    float* ccol = arow + MDIM;

    hipLaunchKernelGGL(convert_rows, dim3(MDIM), dim3(256), 0, stream, x, xb, arow);
    hipLaunchKernelGGL(convert_rows, dim3(NDIM), dim3(256), 0, stream, sv, svb, ccol);
    hipLaunchKernelGGL(rbf_gemm, dim3((MDIM / 128) * (NDIM / 128)), dim3(256), 0,
                       stream, xb, svb, arow, ccol, out);
}

// Round 9
// 187.020 us; speedup vs baseline: 1.1602x; 1.1602x over previous
//
#include <hip/hip_runtime.h>
#include <stdint.h>

#define GAMMA 0.002f
#define MDIM 4096
#define NDIM 8192
#define KDIM 512

typedef short v8s __attribute__((ext_vector_type(8)));
typedef float v4f __attribute__((ext_vector_type(4)));

__device__ __forceinline__ unsigned short f32_to_bf16_rne(float f) {
    union { float f; uint32_t u; } v; v.f = f;
    uint32_t u = v.u;
    return (unsigned short)((u + 0x7fffu + ((u >> 16) & 1u)) >> 16);
}

__device__ __forceinline__ void gl_lds16(const void* g, void* l) {
    __builtin_amdgcn_global_load_lds(
        (const __attribute__((address_space(1))) uint32_t*)g,
        (__attribute__((address_space(3))) uint32_t*)l, 16, 0, 0);
}

// One block per row: convert 512 fp32 -> bf16 (RNE) and emit -gamma*sum(x^2).
__global__ __launch_bounds__(256) void convert_rows(
    const float* __restrict__ in, unsigned short* __restrict__ outb,
    float* __restrict__ neg_g_sq) {
    int row = blockIdx.x;
    const float* src = in + (size_t)row * KDIM;
    unsigned short* dst = outb + (size_t)row * KDIM;
    int t = threadIdx.x;
    float2 f = ((const float2*)src)[t];
    ushort2 b;
    b.x = f32_to_bf16_rne(f.x);
    b.y = f32_to_bf16_rne(f.y);
    ((ushort2*)dst)[t] = b;
    float s = f.x * f.x + f.y * f.y;
    #pragma unroll
    for (int off = 32; off > 0; off >>= 1) s += __shfl_down(s, off, 64);
    __shared__ float red[4];
    if ((t & 63) == 0) red[t >> 6] = s;
    __syncthreads();
    if (t == 0) neg_g_sq[row] = -GAMMA * (red[0] + red[1] + red[2] + red[3]);
}

// v7: v5 schedule (BK=32, triple buffer, vmcnt(4), L2 partition, setprio,
// 3 blocks/CU) + paired-row LDS geometry:
//   LDS super-row r (128 B) = logical rows r and r+64 of the 128x32 tile,
//   granule s = (hi*4 + kchunk) ^ (r&7)  (3-bit XOR, m201-class swizzle).
//   -> fragment ds_read_b128: 16 lanes over 8 granule cols x 2 = b128 floor
//      (conflict-free; v5's 64-B rows allowed only 2-bit XOR = 2x cost).
//   -> staging source (inverse-swizzled, rule 21) still issues 16x 64-B
//      segments per wave — byte-identical coalescing to v5 (v6's regression
//      was the 16-B/1024-B-stride scatter: FETCH 40 MB, 2 TB/s, gemm 92 us).
// Epilogue: direct v4f stores (v6-verified; spares the LDS pipe).
// C[m,n] = exp(arow[m] + ccol[n] + 2*gamma*dot(x[m], sv[n]))
__global__ __launch_bounds__(256, 3) void rbf_gemm(
    const unsigned short* __restrict__ A,   // [4096,512] bf16
    const unsigned short* __restrict__ B,   // [8192,512] bf16
    const float* __restrict__ arow,         // [4096]  = -g*||x||^2
    const float* __restrict__ ccol,         // [8192]  = -g*||sv||^2
    float* __restrict__ out) {

    // LDS: 3 buffers x (A 8 KiB + B 8 KiB) = 48 KiB at 0..49151
    //      sb_r (128 f32) at 49152, sb_c (128 f32) at 49664.  total 50176 B.
    __shared__ __align__(16) char smem[50176];

    const int tid  = threadIdx.x;
    const int lane = tid & 63;
    const int wave = tid >> 6;          // 0..3
    const int wm   = wave >> 1;         // 0..1 : 64-row slice
    const int wn   = wave & 1;          // 0..1 : 64-col slice

    // L2-aware partition: xcd = bid&7 (round-robin dispatch), region 16m x 16n.
    const int bid = blockIdx.x;
    const int xcd = bid & 7;
    const int idx = bid >> 3;                       // 0..255 within region
    const int mt  = ((xcd & 1) << 4) | (idx & 15);  // 0..31
    const int nt  = ((xcd >> 1) << 4) | (idx >> 4); // 0..63
    const int row0 = mt << 7;
    const int col0 = nt << 7;

    // ---- staging (inverse-swizzled source, linear LDS dest tid*16/+4096) ----
    // granule g=tid: super-row rG=tid>>3 (0..31), stored col sG=tid&7;
    // logical col lG = sG ^ (rG&7) -> row-half hiG, k-chunk cG.
    // granule g+256: super-row rG+32, same sG -> same lG (32 = 0 mod 8),
    // so source is simply +32 rows (= +32768 B).
    const int rG  = tid >> 3;
    const int sG  = tid & 7;
    const int lG  = sG ^ (rG & 7);
    const int hiG = lG >> 2;
    const int cG  = lG & 3;
    const char* aS = (const char*)A + ((size_t)(row0 + rG + hiG * 64) << 10) + (cG << 4);
    const char* bS = (const char*)B + ((size_t)(col0 + rG + hiG * 64) << 10) + (cG << 4);
    char* dA = smem + tid * 16;
    char* dB = smem + 8192 + tid * 16;

    #define STAGE(t)                                                          \
      do {                                                                    \
        const int _b = ((t) % 3) * 16384;                                     \
        const char* _sa = aS + (t) * 64;                                      \
        const char* _sb = bS + (t) * 64;                                      \
        gl_lds16(_sa,          dA + _b);                                      \
        gl_lds16(_sa + 32768,  dA + _b + 4096);                               \
        gl_lds16(_sb,          dB + _b);                                      \
        gl_lds16(_sb + 32768,  dB + _b + 4096);                               \
      } while (0)

    // ---- fragment addresses: super-row l15 (+i*16), granule (wm*4+q)^(l15&7)
    const int q   = lane >> 4;          // 0..3 : k-chunk
    const int l15 = lane & 15;
    const int aOff = l15 * 128 + ((((wm << 2) | q) ^ (l15 & 7)) << 4);         // + i*2048
    const int bOff = 8192 + l15 * 128 + ((((wn << 2) | q) ^ (l15 & 7)) << 4);  // + j*2048

    v4f acc[4][4];
    #pragma unroll
    for (int i = 0; i < 4; ++i)
        #pragma unroll
        for (int j = 0; j < 4; ++j) acc[i][j] = (v4f)0.0f;

    // prologue: 2 tiles in flight; bias loads; wait tile0 (vmcnt: 8 out, keep 4)
    STAGE(0); STAGE(1);
    if (tid < 128) ((float*)(smem + 49152))[tid] = arow[row0 + tid];
    else           ((float*)(smem + 49664))[tid - 128] = ccol[col0 + tid - 128];
    asm volatile("s_waitcnt vmcnt(4)" ::: "memory");
    __builtin_amdgcn_s_barrier();

    #pragma unroll
    for (int t = 0; t < 16; ++t) {
        if (t + 2 < 16) STAGE(t + 2);
        const int bo = (t % 3) * 16384;
        v8s af[4], bf[4];
        #pragma unroll
        for (int i = 0; i < 4; ++i) af[i] = *(const v8s*)(smem + bo + aOff + i * 2048);
        #pragma unroll
        for (int j = 0; j < 4; ++j) bf[j] = *(const v8s*)(smem + bo + bOff + j * 2048);
        __builtin_amdgcn_s_setprio(1);
        #pragma unroll
        for (int i = 0; i < 4; ++i)
            #pragma unroll
            for (int j = 0; j < 4; ++j)
                acc[i][j] = __builtin_amdgcn_mfma_f32_16x16x32_bf16(
                    bf[j], af[i], acc[i][j], 0, 0, 0);
        __builtin_amdgcn_s_setprio(0);
        if (t < 14)      asm volatile("s_waitcnt vmcnt(4)" ::: "memory");
        else if (t == 14) asm volatile("s_waitcnt vmcnt(0)" ::: "memory");
        __builtin_amdgcn_s_barrier();
    }
    #undef STAGE

    // ---- epilogue: bias+exp in-register, direct v4f stores (no LDS pass)
    const float tg = 2.0f * GAMMA;
    const float* sbr = (const float*)(smem + 49152);
    const float* sbc = (const float*)(smem + 49664);
    #pragma unroll
    for (int i = 0; i < 4; ++i) {
        const int r_l = wm * 64 + i * 16 + l15;
        const float ra = sbr[r_l];
        float* gp = out + (size_t)(row0 + r_l) * NDIM + col0 + wn * 64 + (q << 2);
        #pragma unroll
        for (int j = 0; j < 4; ++j) {
            v4f o;
            #pragma unroll
            for (int v = 0; v < 4; ++v) {
                const int c_l = wn * 64 + j * 16 + (q << 2) + v;
                o[v] = __expf(fmaf(tg, acc[i][j][v], ra + sbc[c_l]));
            }
            *(v4f*)(gp + j * 16) = o;
        }
    }
}

extern "C" void kernel_launch(void* const* d_in, const int* in_sizes, int n_in,
                              void* d_out, int out_size, void* d_ws, size_t ws_size,
                              hipStream_t stream) {
    const float* x  = (const float*)d_in[0];   // [4096,512]
    const float* sv = (const float*)d_in[1];   // [8192,512]
    float* out = (float*)d_out;

    // ws layout: xb (4 MiB) | svb (8 MiB) | arow (16 KiB) | ccol (32 KiB)
    unsigned short* xb  = (unsigned short*)d_ws;
    unsigned short* svb = xb + (size_t)MDIM * KDIM;
    float* arow = (float*)(svb + (size_t)NDIM * KDIM);
    float* ccol = arow + MDIM;

    hipLaunchKernelGGL(convert_rows, dim3(MDIM), dim3(256), 0, stream, x, xb, arow);
    hipLaunchKernelGGL(convert_rows, dim3(NDIM), dim3(256), 0, stream, sv, svb, ccol);
    hipLaunchKernelGGL(rbf_gemm, dim3((MDIM / 128) * (NDIM / 128)), dim3(256), 0,
                       stream, xb, svb, arow, ccol, out);
}